// Round 14
// baseline (124.937 us; speedup 1.0000x reference)
//
#include <hip/hip_runtime.h>

#define NROWS 131072
#define DDIM  64
#define KCTR  512
#define OUT_W 577                 /* 1 + 64 + 512 */
#define TILE_ROWS 16
#define NTILES (NROWS / TILE_ROWS)   /* 8192 */
#define BLK 256                      /* 4 waves/block */
#define GRID 1024                    /* 4096 waves -> 2 tiles each, exact */
#define TOTAL_WAVES (GRID * 4)
#define K_HALF_LN2 0.34657359027997264f   /* 0.5*ln(2) */

typedef __attribute__((ext_vector_type(8))) short bfrag8;
typedef __attribute__((ext_vector_type(4))) float f32x4;
typedef __attribute__((ext_vector_type(2))) float f32x2;

// 16B vector store/load with only 4B alignment (out rows are 2308B-strided).
struct __attribute__((packed, aligned(4))) F4a4 { f32x4 v; };

__device__ __forceinline__ short f2bf(float f) {
    union { float f; unsigned u; } v; v.f = f;
    return (short)((v.u + 0x8000u) >> 16);   // round-to-nearest
}

// Prep: center norms (f32) + cbf = bf16(-2*centers), into d_ws (L2-resident).
__global__ __launch_bounds__(256) void prep_kernel(
    const float* __restrict__ centers, float* __restrict__ cnorm,
    short* __restrict__ cbf)
{
    int k = blockIdx.x * 256 + threadIdx.x;
    if (k >= KCTR) return;
    const float* c = centers + (size_t)k * DDIM;
    short* o = cbf + (size_t)k * DDIM;
    float s = 0.f;
#pragma unroll
    for (int i0 = 0; i0 < DDIM; i0 += 8) {
        bfrag8 b;
#pragma unroll
        for (int j = 0; j < 8; ++j) {
            float v = c[i0 + j];
            s += v * v;
            b[j] = f2bf(-2.f * v);
        }
        *reinterpret_cast<bfrag8*>(o + i0) = b;
    }
    cnorm[k] = s;
}

// Wave-autonomous main kernel: each wave owns 16 rows x 512 centers; the only
// barrier is the one-time cnorm staging. Waves de-phase freely; stores issue
// continuously; vmcnt backpressure self-throttles at HBM rate.
__global__ __launch_bounds__(BLK, 4) void dicrbf_wave(
    const float* __restrict__ data,
    const float* __restrict__ cnorm_g,
    const short* __restrict__ cbf,
    float* __restrict__ out)
{
    __shared__ float s_cnorm[KCTR];                     // 2 KB, read-only after stage
    __shared__ __align__(16) float s_scr[4][2][256];    // per-wave dbuf transpose scratch, 8 KB

    const int t    = threadIdx.x;
    const int lane = t & 63;
    const int wid  = t >> 6;
    const int l15  = lane & 15;
    const int lhi  = lane >> 4;

    // stage cnorm -> LDS (2 f32/thread)
    {
        f32x2 c = *reinterpret_cast<const f32x2*>(cnorm_g + 2 * t);
        *reinterpret_cast<f32x2*>(&s_cnorm[2 * t]) = c;
    }
    __syncthreads();   // the ONLY barrier in this kernel

    const int gwave = blockIdx.x * 4 + wid;
    float* wscr0 = &s_scr[wid][0][0];
    float* wscr1 = &s_scr[wid][1][0];
    const char* cb = reinterpret_cast<const char*>(cbf);

    for (int ti = 0; ti < 2; ++ti) {
        const int tile = gwave + ti * TOTAL_WAVES;

        // ---- Load own 16 rows: lane(l15,lhi) holds row l15, cols lhi*8..+7
        // and 32+lhi*8..+7 (16 f32 in 4 dwordx4) ----
        const size_t row = (size_t)tile * TILE_ROWS + l15;
        const float* dp = data + row * DDIM + lhi * 8;
        const f32x4 u0 = *reinterpret_cast<const f32x4*>(dp);
        const f32x4 u1 = *reinterpret_cast<const f32x4*>(dp + 4);
        const f32x4 u2 = *reinterpret_cast<const f32x4*>(dp + 32);
        const f32x4 u3 = *reinterpret_cast<const f32x4*>(dp + 36);

        // xsq: own 16 squares + reduce over the 4-lane lhi group
        float s = 0.f;
#pragma unroll
        for (int j = 0; j < 4; ++j)
            s += u0[j]*u0[j] + u1[j]*u1[j] + u2[j]*u2[j] + u3[j]*u3[j];
        s += __shfl_xor(s, 16);
        s += __shfl_xor(s, 32);
        const float xsq = s;

        // B-frags in-register (row=l15, k = ks*32 + lhi*8 + j)
        bfrag8 b0, b1;
#pragma unroll
        for (int j = 0; j < 4; ++j) {
            b0[j]     = f2bf(u0[j]);
            b0[4 + j] = f2bf(u1[j]);
            b1[j]     = f2bf(u2[j]);
            b1[4 + j] = f2bf(u3[j]);
        }

        // passthrough + ones (own row, own cols)
        float* orow = out + row * OUT_W;
        reinterpret_cast<F4a4*>(orow + 1 + lhi * 8)->v      = u0;
        reinterpret_cast<F4a4*>(orow + 1 + lhi * 8 + 4)->v  = u1;
        reinterpret_cast<F4a4*>(orow + 33 + lhi * 8)->v     = u2;
        reinterpret_cast<F4a4*>(orow + 33 + lhi * 8 + 4)->v = u3;
        if (lhi == 0) orow[0] = 1.0f;

        // transposed-store base: lane l -> (row tile*16 + (l>>2), col chunk l&3)
        const size_t srow = (size_t)tile * TILE_ROWS + (lane >> 2);
        float* ost = out + srow * OUT_W + 65 + (lane & 3) * 4;

        // A-frag prefetch (cbf bytes: (mf*16+l15)*128 + ks*64 + lhi*16)
        bfrag8 a0 = *reinterpret_cast<const bfrag8*>(cb + ((0 * 16 + l15) * 128 + lhi * 16));
        bfrag8 a1 = *reinterpret_cast<const bfrag8*>(cb + ((0 * 16 + l15) * 128 + 64 + lhi * 16));

#pragma unroll 2
        for (int mf = 0; mf < 32; ++mf) {
            bfrag8 na0 = a0, na1 = a1;
            if (mf < 31) {
                na0 = *reinterpret_cast<const bfrag8*>(cb + (((mf + 1) * 16 + l15) * 128 + lhi * 16));
                na1 = *reinterpret_cast<const bfrag8*>(cb + (((mf + 1) * 16 + l15) * 128 + 64 + lhi * 16));
            }

            const f32x4 cn4 = *reinterpret_cast<const f32x4*>(&s_cnorm[mf * 16 + lhi * 4]);
            f32x4 acc;
#pragma unroll
            for (int k = 0; k < 4; ++k) acc[k] = xsq + cn4[k];
            acc = __builtin_amdgcn_mfma_f32_16x16x32_bf16(a0, b0, acc, 0, 0, 0);
            acc = __builtin_amdgcn_mfma_f32_16x16x32_bf16(a1, b1, acc, 0, 0, 0);

            f32x4 w;
#pragma unroll
            for (int k = 0; k < 4; ++k) {
                const float d2 = fmaxf(acc[k], 1e-30f);   // clamps negatives; ~0 stays ~0
                w[k] = (K_HALF_LN2 * d2) * __log2f(d2);
            }

            // in-wave transpose through private LDS scratch (dbuf by mf parity;
            // per-wave lgkmcnt ordering only — no barrier)
            float* scr = (mf & 1) ? wscr1 : wscr0;
            *reinterpret_cast<f32x4*>(scr + l15 * 16 + lhi * 4) = w;
            asm volatile("s_waitcnt lgkmcnt(0)" ::: "memory");
            __builtin_amdgcn_sched_barrier(0);
            const f32x4 tw = *reinterpret_cast<const f32x4*>(scr + lane * 4);

            // coalesced-by-row store: 16 x 64B segments per instruction
            reinterpret_cast<F4a4*>(ost + mf * 16)->v = tw;

            a0 = na0; a1 = na1;
        }
    }
}

extern "C" void kernel_launch(void* const* d_in, const int* in_sizes, int n_in,
                              void* d_out, int out_size, void* d_ws, size_t ws_size,
                              hipStream_t stream) {
    const float* data    = (const float*)d_in[0];
    const float* centers = (const float*)d_in[1];
    float* out = (float*)d_out;

    float* cnorm = (float*)d_ws;                     // 512 f32 = 2 KB
    short* cbf   = (short*)((char*)d_ws + 2048);     // 512*64 bf16 = 64 KB

    hipLaunchKernelGGL(prep_kernel, dim3(2), dim3(256), 0, stream, centers, cnorm, cbf);
    hipLaunchKernelGGL(dicrbf_wave, dim3(GRID), dim3(BLK), 0, stream,
                       data, cnorm, cbf, out);
}